// Round 3
// baseline (599.659 us; speedup 1.0000x reference)
//
#include <hip/hip_runtime.h>

// ---------------------------------------------------------------------------
// GEMM pass: Xl[row*CB + c] = sum_k X[row][k] * W[k][c0+c],  c in [0, CB)
// Block = 256 threads, 16 rows/block. W col-block + 16 X rows staged in LDS.
// ---------------------------------------------------------------------------
template <int CB>
__global__ __launch_bounds__(256) void gemm_kernel(
    const float* __restrict__ X, const float* __restrict__ W,
    float* __restrict__ Xl, int Nrows, int c0) {
  __shared__ float ldsW[128 * CB];
  __shared__ float ldsX[16][128];

  const int tid = threadIdx.x;

  for (int i = tid; i < 128 * CB; i += 256) {
    const int k = i / CB;
    const int c = i % CB;
    ldsW[i] = W[k * 64 + c0 + c];
  }

  const int row0 = blockIdx.x * 16;
  {
    const int r    = tid >> 4;         // 0..15
    const int col0 = (tid & 15) * 8;   // 0..120
    const int rr   = row0 + r;
    if (rr < Nrows) {
      const float4 a = *(const float4*)(X + (size_t)rr * 128 + col0);
      const float4 b = *(const float4*)(X + (size_t)rr * 128 + col0 + 4);
      float* dst = &ldsX[r][col0];
      dst[0] = a.x; dst[1] = a.y; dst[2] = a.z; dst[3] = a.w;
      dst[4] = b.x; dst[5] = b.y; dst[6] = b.z; dst[7] = b.w;
    }
  }
  __syncthreads();

  constexpr int RSTEP = 256 / CB;   // CB>=16 => RSTEP<=16
  constexpr int NACC  = CB / 16;    // rows per thread
  const int c  = tid & (CB - 1);
  const int r0 = tid / CB;

  float acc[NACC];
#pragma unroll
  for (int j = 0; j < NACC; ++j) acc[j] = 0.f;

  const float* __restrict__ wc = ldsW + c;
#pragma unroll 8
  for (int k = 0; k < 128; ++k) {
    const float w = wc[k * CB];        // consecutive banks across lanes
#pragma unroll
    for (int j = 0; j < NACC; ++j)
      acc[j] += ldsX[r0 + j * RSTEP][k] * w;   // wave-broadcast (CB=64)
  }

#pragma unroll
  for (int j = 0; j < NACC; ++j) {
    const int rr = row0 + r0 + j * RSTEP;
    if (rr < Nrows) Xl[(size_t)rr * CB + c] = acc[j];
  }
}

// ---------------------------------------------------------------------------
// Scatter 1: Xe[e*CB + c] += Xl[v*CB + c] * degE[e] * W_edge[e]
// (per-edge scale distributes over the segment sum)
// ---------------------------------------------------------------------------
template <int CB>
__global__ __launch_bounds__(256) void scatter1_kernel(
    const float* __restrict__ Xl, const int* __restrict__ vertex,
    const int* __restrict__ edges, const float* __restrict__ degE,
    const float* __restrict__ W_edge, float* __restrict__ Xe, int nnz) {
  const long long t = (long long)blockIdx.x * 256 + threadIdx.x;
  const int nz = (int)(t / CB);
  if (nz >= nnz) return;
  const int c = (int)(t & (CB - 1));
  const int v = vertex[nz];
  const int e = edges[nz];
  const float s = degE[e] * W_edge[e];
  atomicAdd(&Xe[(size_t)e * CB + c], Xl[(size_t)v * CB + c] * s);
}

// ---------------------------------------------------------------------------
// Scatter 2: out[v*64 + c0 + c] += Xe[e*CB + c]   (out pre-zeroed)
// ---------------------------------------------------------------------------
template <int CB>
__global__ __launch_bounds__(256) void scatter2_kernel(
    const float* __restrict__ Xe, const int* __restrict__ vertex,
    const int* __restrict__ edges, float* __restrict__ out, int nnz, int c0) {
  const long long t = (long long)blockIdx.x * 256 + threadIdx.x;
  const int nz = (int)(t / CB);
  if (nz >= nnz) return;
  const int c = (int)(t & (CB - 1));
  const int v = vertex[nz];
  const int e = edges[nz];
  atomicAdd(&out[(size_t)v * 64 + c0 + c], Xe[(size_t)e * CB + c]);
}

// ---------------------------------------------------------------------------
// Finalize (in place): out[row*64 + c0 + c] *= degV[row], 2 cols/thread
// ---------------------------------------------------------------------------
template <int CB>
__global__ __launch_bounds__(256) void finalize_kernel(
    float* __restrict__ out, const float* __restrict__ degV, int Nrows, int c0) {
  const int t = blockIdx.x * 256 + threadIdx.x;
  const int row = t / (CB / 2);
  if (row >= Nrows) return;
  const int c = (t % (CB / 2)) * 2;
  float* p = out + (size_t)row * 64 + c0 + c;
  const float dv = degV[row];
  float2 v = *(float2*)p;
  v.x *= dv; v.y *= dv;
  *(float2*)p = v;
}

// ---------------------------------------------------------------------------
template <int CB>
static void run_all(const float* X, const int* vertex, const int* edges,
                    const float* W, const float* degE, const float* degV,
                    const float* W_edge, float* out, int N, int E, int nnz,
                    void* d_ws, hipStream_t stream) {
  float* Xl = (float*)d_ws;            // N*CB f32
  float* Xe = Xl + (size_t)N * CB;     // E*CB f32

  const int gemm_blocks = (N + 15) / 16;
  const long long sthreads = (long long)nnz * CB;
  const int sblocks = (int)((sthreads + 255) / 256);
  const int fblocks = (int)(((long long)N * (CB / 2) + 255) / 256);

  hipMemsetAsync(out, 0, (size_t)N * 64 * sizeof(float), stream);

  for (int c0 = 0; c0 < 64; c0 += CB) {
    hipMemsetAsync(Xe, 0, (size_t)E * CB * sizeof(float), stream);
    gemm_kernel<CB><<<gemm_blocks, 256, 0, stream>>>(X, W, Xl, N, c0);
    scatter1_kernel<CB><<<sblocks, 256, 0, stream>>>(Xl, vertex, edges, degE, W_edge, Xe, nnz);
    scatter2_kernel<CB><<<sblocks, 256, 0, stream>>>(Xe, vertex, edges, out, nnz, c0);
    finalize_kernel<CB><<<fblocks, 256, 0, stream>>>(out, degV, N, c0);
  }
}

extern "C" void kernel_launch(void* const* d_in, const int* in_sizes, int n_in,
                              void* d_out, int out_size, void* d_ws, size_t ws_size,
                              hipStream_t stream) {
  const float* X      = (const float*)d_in[0];
  const int*   vertex = (const int*)d_in[1];
  const int*   edges  = (const int*)d_in[2];
  const float* W      = (const float*)d_in[3];
  const float* degE   = (const float*)d_in[4];
  const float* degV   = (const float*)d_in[5];
  const float* W_edge = (const float*)d_in[6];
  float* out = (float*)d_out;

  const int nnz = in_sizes[1];
  const int E   = in_sizes[4];
  const int N   = in_sizes[5];

  // f32 scratch per output column: Xl(N) + Xe(E)
  const size_t per_col = (size_t)((size_t)N + (size_t)E) * sizeof(float);

  int CB = 64;
  if (per_col * 64 > ws_size) CB = 32;
  if (per_col * 32 > ws_size) CB = 16;   // 7.7 MB floor for this problem

  switch (CB) {
    case 64: run_all<64>(X, vertex, edges, W, degE, degV, W_edge, out, N, E, nnz, d_ws, stream); break;
    case 32: run_all<32>(X, vertex, edges, W, degE, degV, W_edge, out, N, E, nnz, d_ws, stream); break;
    default: run_all<16>(X, vertex, edges, W, degE, degV, W_edge, out, N, E, nnz, d_ws, stream); break;
  }
}

// Round 4
// 466.179 us; speedup vs baseline: 1.2863x; 1.2863x over previous
//
#include <hip/hip_runtime.h>
#include <hip/hip_bf16.h>

typedef __hip_bfloat16 bf16;
__device__ __forceinline__ float bf2f(bf16 v) { return __bfloat162float(v); }

// ===========================================================================
// CSR build: combined histogram/scan over M = E + N segments.
// Edge segments occupy perm[0 .. nnz), vertex segments perm[nnz .. 2*nnz).
// ===========================================================================

__global__ __launch_bounds__(256) void hist_kernel(
    const int* __restrict__ vertex, const int* __restrict__ edges,
    int* __restrict__ counts, int nnz, int E) {
  const int i = blockIdx.x * 256 + threadIdx.x;
  if (i >= nnz) return;
  atomicAdd(&counts[edges[i]], 1);
  atomicAdd(&counts[E + vertex[i]], 1);
}

// 2048 elements per block: thread-local 8 + Hillis-Steele over 256 threads.
__global__ __launch_bounds__(256) void scan_blocks_kernel(
    const int* __restrict__ counts, int* __restrict__ offs,
    int* __restrict__ bsums, int M) {
  __shared__ int lds[256];
  const int tid  = threadIdx.x;
  const int base = blockIdx.x * 2048 + tid * 8;
  int v[8]; int tsum = 0;
#pragma unroll
  for (int j = 0; j < 8; ++j) {
    v[j] = (base + j < M) ? counts[base + j] : 0;
    tsum += v[j];
  }
  lds[tid] = tsum;
  __syncthreads();
  for (int off = 1; off < 256; off <<= 1) {
    int t = (tid >= off) ? lds[tid - off] : 0;
    __syncthreads();
    lds[tid] += t;
    __syncthreads();
  }
  int run = lds[tid] - tsum;   // exclusive prefix for this thread
#pragma unroll
  for (int j = 0; j < 8; ++j) {
    if (base + j < M) offs[base + j] = run;
    run += v[j];
  }
  if (tid == 255) bsums[blockIdx.x] = lds[255];
}

__global__ void scan_sums_kernel(int* __restrict__ bsums, int* __restrict__ offs,
                                 int NB, int M) {
  if (threadIdx.x == 0 && blockIdx.x == 0) {
    int run = 0;
    for (int b = 0; b < NB; ++b) { int t = bsums[b]; bsums[b] = run; run += t; }
    offs[M] = run;   // == 2*nnz
  }
}

__global__ __launch_bounds__(256) void scan_add_kernel(
    int* __restrict__ offs, int* __restrict__ pos,
    const int* __restrict__ bsums, int M) {
  const int base = blockIdx.x * 2048 + threadIdx.x * 8;
  const int add = bsums[blockIdx.x];
#pragma unroll
  for (int j = 0; j < 8; ++j) {
    if (base + j < M) {
      const int t = offs[base + j] + add;
      offs[base + j] = t;
      pos[base + j] = t;
    }
  }
}

__global__ __launch_bounds__(256) void fill_kernel(
    const int* __restrict__ vertex, const int* __restrict__ edges,
    int* __restrict__ pos, int* __restrict__ perm, int nnz, int E) {
  const int i = blockIdx.x * 256 + threadIdx.x;
  if (i >= nnz) return;
  const int e = edges[i];
  const int v = vertex[i];
  const int p1 = atomicAdd(&pos[e], 1);
  perm[p1] = v;                       // edge-grouped: store vertex id
  const int p2 = atomicAdd(&pos[E + v], 1);
  perm[p2] = e;                       // vertex-grouped: store edge id
}

// ===========================================================================
// GEMM: Xl[N,64] (bf16) = X[N,128] (f32) @ W[128,64] (f32). 32 rows/block.
// ===========================================================================
__global__ __launch_bounds__(256) void gemm_kernel(
    const float* __restrict__ X, const float* __restrict__ W,
    bf16* __restrict__ Xl, int Nrows) {
  __shared__ float ldsW[128 * 64];   // 32 KB
  __shared__ float ldsX[32][128];    // 16 KB

  const int tid = threadIdx.x;
  for (int i = tid; i < 128 * 64; i += 256) ldsW[i] = W[i];

  const int row0 = blockIdx.x * 32;
  {
    const int r    = tid >> 3;           // 0..31
    const int col0 = (tid & 7) * 16;     // 0..112
    const int rr   = row0 + r;
    if (rr < Nrows) {
      const float* src = X + (size_t)rr * 128 + col0;
      float* dst = &ldsX[r][col0];
#pragma unroll
      for (int q = 0; q < 4; ++q)
        *(float4*)(dst + q * 4) = *(const float4*)(src + q * 4);
    }
  }
  __syncthreads();

  const int c  = tid & 63;
  const int r0 = tid >> 6;       // 0..3; rows r0 + 4*j
  float acc[8];
#pragma unroll
  for (int j = 0; j < 8; ++j) acc[j] = 0.f;

  const float* __restrict__ wc = ldsW + c;
#pragma unroll 4
  for (int k = 0; k < 128; ++k) {
    const float w = wc[k * 64];
#pragma unroll
    for (int j = 0; j < 8; ++j)
      acc[j] += ldsX[r0 + j * 4][k] * w;
  }

#pragma unroll
  for (int j = 0; j < 8; ++j) {
    const int rr = row0 + r0 + j * 4;
    if (rr < Nrows) Xl[(size_t)rr * 64 + c] = __float2bfloat16(acc[j]);
  }
}

// ===========================================================================
// Gather 1: one wave per hyperedge. Xe[e] = degE[e]*W_edge[e] * sum_v Xl[v]
// ===========================================================================
__global__ __launch_bounds__(256) void gather_e_kernel(
    const bf16* __restrict__ Xl, const int* __restrict__ perm,
    const int* __restrict__ offs, const float* __restrict__ degE,
    const float* __restrict__ W_edge, float* __restrict__ Xe, int E) {
  const int gtid = blockIdx.x * 256 + threadIdx.x;
  const int e    = gtid >> 6;
  const int lane = gtid & 63;
  if (e >= E) return;

  const int beg = offs[e];
  const int end = offs[e + 1];
  float acc = 0.f;

  for (int base = beg; base < end; base += 64) {
    const int n = min(64, end - base);
    const int idx = (lane < n) ? perm[base + lane] : 0;
    int jj = 0;
    for (; jj + 4 <= n; jj += 4) {
      const int v0 = __shfl(idx, jj + 0, 64);
      const int v1 = __shfl(idx, jj + 1, 64);
      const int v2 = __shfl(idx, jj + 2, 64);
      const int v3 = __shfl(idx, jj + 3, 64);
      const float f0 = bf2f(Xl[(size_t)v0 * 64 + lane]);
      const float f1 = bf2f(Xl[(size_t)v1 * 64 + lane]);
      const float f2 = bf2f(Xl[(size_t)v2 * 64 + lane]);
      const float f3 = bf2f(Xl[(size_t)v3 * 64 + lane]);
      acc += (f0 + f1) + (f2 + f3);
    }
    for (; jj < n; ++jj) {
      const int v = __shfl(idx, jj, 64);
      acc += bf2f(Xl[(size_t)v * 64 + lane]);
    }
  }
  const float s = degE[e] * W_edge[e];
  Xe[(size_t)e * 64 + lane] = acc * s;
}

// ===========================================================================
// Gather 2: one wave per node. out[v] = degV[v] * sum_e Xe[e]
// ===========================================================================
__global__ __launch_bounds__(256) void gather_v_kernel(
    const float* __restrict__ Xe, const int* __restrict__ perm,
    const int* __restrict__ offs, const float* __restrict__ degV,
    float* __restrict__ out, int N, int E) {
  const int gtid = blockIdx.x * 256 + threadIdx.x;
  const int v    = gtid >> 6;
  const int lane = gtid & 63;
  if (v >= N) return;

  const int beg = offs[E + v];
  const int end = offs[E + v + 1];
  float acc = 0.f;

  for (int base = beg; base < end; base += 64) {
    const int n = min(64, end - base);
    const int idx = (lane < n) ? perm[base + lane] : 0;
    int jj = 0;
    for (; jj + 4 <= n; jj += 4) {
      const int e0 = __shfl(idx, jj + 0, 64);
      const int e1 = __shfl(idx, jj + 1, 64);
      const int e2 = __shfl(idx, jj + 2, 64);
      const int e3 = __shfl(idx, jj + 3, 64);
      const float f0 = Xe[(size_t)e0 * 64 + lane];
      const float f1 = Xe[(size_t)e1 * 64 + lane];
      const float f2 = Xe[(size_t)e2 * 64 + lane];
      const float f3 = Xe[(size_t)e3 * 64 + lane];
      acc += (f0 + f1) + (f2 + f3);
    }
    for (; jj < n; ++jj) {
      const int e = __shfl(idx, jj, 64);
      acc += Xe[(size_t)e * 64 + lane];
    }
  }
  out[(size_t)v * 64 + lane] = acc * degV[v];
}

// ===========================================================================
extern "C" void kernel_launch(void* const* d_in, const int* in_sizes, int n_in,
                              void* d_out, int out_size, void* d_ws, size_t ws_size,
                              hipStream_t stream) {
  const float* X      = (const float*)d_in[0];
  const int*   vertex = (const int*)d_in[1];
  const int*   edges  = (const int*)d_in[2];
  const float* W      = (const float*)d_in[3];
  const float* degE   = (const float*)d_in[4];
  const float* degV   = (const float*)d_in[5];
  const float* W_edge = (const float*)d_in[6];
  float* out = (float*)d_out;

  const int nnz = in_sizes[1];
  const int E   = in_sizes[4];
  const int N   = in_sizes[5];
  const int M   = E + N;
  const int NB  = (M + 2047) / 2048;

  // Workspace layout (~27.5 MB for N=100k, E=20k, nnz=1M; round 3 proved
  // ws_size >= 30.7 MB):
  char* p = (char*)d_ws;
  auto alloc = [&](size_t bytes) -> void* {
    void* r = (void*)p;
    p += (bytes + 255) & ~(size_t)255;
    return r;
  };
  int*   counts = (int*)alloc((size_t)M * 4);
  int*   offs   = (int*)alloc((size_t)(M + 1) * 4);
  int*   pos    = (int*)alloc((size_t)M * 4);
  int*   bsums  = (int*)alloc(4096);
  int*   perm   = (int*)alloc((size_t)2 * nnz * 4);
  bf16*  Xl     = (bf16*)alloc((size_t)N * 64 * 2);
  float* Xe     = (float*)alloc((size_t)E * 64 * 4);

  const int nzb = (nnz + 255) / 256;

  hipMemsetAsync(counts, 0, (size_t)M * 4, stream);
  hist_kernel<<<nzb, 256, 0, stream>>>(vertex, edges, counts, nnz, E);
  scan_blocks_kernel<<<NB, 256, 0, stream>>>(counts, offs, bsums, M);
  scan_sums_kernel<<<1, 64, 0, stream>>>(bsums, offs, NB, M);
  scan_add_kernel<<<NB, 256, 0, stream>>>(offs, pos, bsums, M);
  fill_kernel<<<nzb, 256, 0, stream>>>(vertex, edges, pos, perm, nnz, E);

  gemm_kernel<<<(N + 31) / 32, 256, 0, stream>>>(X, W, Xl, N);
  gather_e_kernel<<<(E + 3) / 4, 256, 0, stream>>>(Xl, perm, offs, degE, W_edge, Xe, E);
  gather_v_kernel<<<(N + 3) / 4, 256, 0, stream>>>(Xe, perm, offs, degV, out, N, E);
}

// Round 5
// 395.527 us; speedup vs baseline: 1.5161x; 1.1786x over previous
//
#include <hip/hip_runtime.h>
#include <hip/hip_bf16.h>

typedef __hip_bfloat16 bf16;
__device__ __forceinline__ float bf2f(bf16 v) { return __bfloat162float(v); }

#define NPART 8        // XCD count; blockIdx % 8 ~ round-robin XCD heuristic
#define CHUNK 8192     // incidences per chunk (32 iters/thread @ 256 threads)

// ===========================================================================
// Histogram, destination-partitioned: block (chunk,part) counts only dests in
// its partition -> counter atomics stay XCD-local.
// ===========================================================================
__global__ __launch_bounds__(256) void hist_kernel(
    const int* __restrict__ vertex, const int* __restrict__ edges,
    int* __restrict__ counts, int nnz, int E, int N) {
  const int part  = blockIdx.x % NPART;
  const int chunk = blockIdx.x / NPART;
  const int eLo = (int)((long long)E * part / NPART);
  const int eHi = (int)((long long)E * (part + 1) / NPART);
  const int vLo = (int)((long long)N * part / NPART);
  const int vHi = (int)((long long)N * (part + 1) / NPART);
  const int iEnd = min(nnz, (chunk + 1) * CHUNK);
  for (int i = chunk * CHUNK + threadIdx.x; i < iEnd; i += 256) {
    const int e = edges[i];
    const int v = vertex[i];
    if (e >= eLo && e < eHi) atomicAdd(&counts[e], 1);
    if (v >= vLo && v < vHi) atomicAdd(&counts[E + v], 1);
  }
}

// 2048 elements per block: thread-local 8 + Hillis-Steele over 256 threads.
__global__ __launch_bounds__(256) void scan_blocks_kernel(
    const int* __restrict__ counts, int* __restrict__ offs,
    int* __restrict__ bsums, int M) {
  __shared__ int lds[256];
  const int tid  = threadIdx.x;
  const int base = blockIdx.x * 2048 + tid * 8;
  int v[8]; int tsum = 0;
#pragma unroll
  for (int j = 0; j < 8; ++j) {
    v[j] = (base + j < M) ? counts[base + j] : 0;
    tsum += v[j];
  }
  lds[tid] = tsum;
  __syncthreads();
  for (int off = 1; off < 256; off <<= 1) {
    int t = (tid >= off) ? lds[tid - off] : 0;
    __syncthreads();
    lds[tid] += t;
    __syncthreads();
  }
  int run = lds[tid] - tsum;
#pragma unroll
  for (int j = 0; j < 8; ++j) {
    if (base + j < M) offs[base + j] = run;
    run += v[j];
  }
  if (tid == 255) bsums[blockIdx.x] = lds[255];
}

__global__ void scan_sums_kernel(int* __restrict__ bsums, int* __restrict__ offs,
                                 int NB, int M) {
  if (threadIdx.x == 0 && blockIdx.x == 0) {
    int run = 0;
    for (int b = 0; b < NB; ++b) { int t = bsums[b]; bsums[b] = run; run += t; }
    offs[M] = run;   // == 2*nnz
  }
}

__global__ __launch_bounds__(256) void scan_add_kernel(
    int* __restrict__ offs, int* __restrict__ pos,
    const int* __restrict__ bsums, int M) {
  const int base = blockIdx.x * 2048 + threadIdx.x * 8;
  const int add = bsums[blockIdx.x];
#pragma unroll
  for (int j = 0; j < 8; ++j) {
    if (base + j < M) {
      const int t = offs[base + j] + add;
      offs[base + j] = t;
      pos[base + j] = t;
    }
  }
}

// ===========================================================================
// CSR fill, destination-partitioned: partition p only writes perm slots of
// segments in its dest range -> per-XCD ~1MB write window stays L2-resident,
// 16 x 4B writes merge into one full-line writeback.
// ===========================================================================
__global__ __launch_bounds__(256) void fill_kernel(
    const int* __restrict__ vertex, const int* __restrict__ edges,
    int* __restrict__ pos, int* __restrict__ perm, int nnz, int E, int N) {
  const int part  = blockIdx.x % NPART;
  const int chunk = blockIdx.x / NPART;
  const int eLo = (int)((long long)E * part / NPART);
  const int eHi = (int)((long long)E * (part + 1) / NPART);
  const int vLo = (int)((long long)N * part / NPART);
  const int vHi = (int)((long long)N * (part + 1) / NPART);
  const int iEnd = min(nnz, (chunk + 1) * CHUNK);
  for (int i = chunk * CHUNK + threadIdx.x; i < iEnd; i += 256) {
    const int e = edges[i];
    const int v = vertex[i];
    if (e >= eLo && e < eHi) {
      const int p1 = atomicAdd(&pos[e], 1);
      perm[p1] = v;                     // edge-grouped: store vertex id
    }
    if (v >= vLo && v < vHi) {
      const int p2 = atomicAdd(&pos[E + v], 1);
      perm[p2] = e;                     // vertex-grouped: store edge id
    }
  }
}

// ===========================================================================
// GEMM: Xl[N,64] (bf16) = X[N,128] (f32) @ W[128,64] (f32). 32 rows/block.
// ===========================================================================
__global__ __launch_bounds__(256) void gemm_kernel(
    const float* __restrict__ X, const float* __restrict__ W,
    bf16* __restrict__ Xl, int Nrows) {
  __shared__ float ldsW[128 * 64];   // 32 KB
  __shared__ float ldsX[32][128];    // 16 KB

  const int tid = threadIdx.x;
  for (int i = tid; i < 128 * 64; i += 256) ldsW[i] = W[i];

  const int row0 = blockIdx.x * 32;
  {
    const int r    = tid >> 3;           // 0..31
    const int col0 = (tid & 7) * 16;     // 0..112
    const int rr   = row0 + r;
    if (rr < Nrows) {
      const float* src = X + (size_t)rr * 128 + col0;
      float* dst = &ldsX[r][col0];
#pragma unroll
      for (int q = 0; q < 4; ++q)
        *(float4*)(dst + q * 4) = *(const float4*)(src + q * 4);
    }
  }
  __syncthreads();

  const int c  = tid & 63;
  const int r0 = tid >> 6;       // 0..3; rows r0 + 4*j
  float acc[8];
#pragma unroll
  for (int j = 0; j < 8; ++j) acc[j] = 0.f;

  const float* __restrict__ wc = ldsW + c;
#pragma unroll 4
  for (int k = 0; k < 128; ++k) {
    const float w = wc[k * 64];
#pragma unroll
    for (int j = 0; j < 8; ++j)
      acc[j] += ldsX[r0 + j * 4][k] * w;
  }

#pragma unroll
  for (int j = 0; j < 8; ++j) {
    const int rr = row0 + r0 + j * 4;
    if (rr < Nrows) Xl[(size_t)rr * 64 + c] = __float2bfloat16(acc[j]);
  }
}

// ===========================================================================
// Gather 1: one wave per hyperedge. Xe[e] = degE[e]*W_edge[e] * sum_v Xl[v]
// ===========================================================================
__global__ __launch_bounds__(256) void gather_e_kernel(
    const bf16* __restrict__ Xl, const int* __restrict__ perm,
    const int* __restrict__ offs, const float* __restrict__ degE,
    const float* __restrict__ W_edge, float* __restrict__ Xe, int E) {
  const int gtid = blockIdx.x * 256 + threadIdx.x;
  const int e    = gtid >> 6;
  const int lane = gtid & 63;
  if (e >= E) return;

  const int beg = offs[e];
  const int end = offs[e + 1];
  float acc = 0.f;

  for (int base = beg; base < end; base += 64) {
    const int n = min(64, end - base);
    const int idx = (lane < n) ? perm[base + lane] : 0;
    int jj = 0;
    for (; jj + 4 <= n; jj += 4) {
      const int v0 = __shfl(idx, jj + 0, 64);
      const int v1 = __shfl(idx, jj + 1, 64);
      const int v2 = __shfl(idx, jj + 2, 64);
      const int v3 = __shfl(idx, jj + 3, 64);
      const float f0 = bf2f(Xl[(size_t)v0 * 64 + lane]);
      const float f1 = bf2f(Xl[(size_t)v1 * 64 + lane]);
      const float f2 = bf2f(Xl[(size_t)v2 * 64 + lane]);
      const float f3 = bf2f(Xl[(size_t)v3 * 64 + lane]);
      acc += (f0 + f1) + (f2 + f3);
    }
    for (; jj < n; ++jj) {
      const int v = __shfl(idx, jj, 64);
      acc += bf2f(Xl[(size_t)v * 64 + lane]);
    }
  }
  const float s = degE[e] * W_edge[e];
  Xe[(size_t)e * 64 + lane] = acc * s;
}

// ===========================================================================
// Gather 2: one wave per node. out[v] = degV[v] * sum_e Xe[e]
// ===========================================================================
__global__ __launch_bounds__(256) void gather_v_kernel(
    const float* __restrict__ Xe, const int* __restrict__ perm,
    const int* __restrict__ offs, const float* __restrict__ degV,
    float* __restrict__ out, int N, int E) {
  const int gtid = blockIdx.x * 256 + threadIdx.x;
  const int v    = gtid >> 6;
  const int lane = gtid & 63;
  if (v >= N) return;

  const int beg = offs[E + v];
  const int end = offs[E + v + 1];
  float acc = 0.f;

  for (int base = beg; base < end; base += 64) {
    const int n = min(64, end - base);
    const int idx = (lane < n) ? perm[base + lane] : 0;
    int jj = 0;
    for (; jj + 4 <= n; jj += 4) {
      const int e0 = __shfl(idx, jj + 0, 64);
      const int e1 = __shfl(idx, jj + 1, 64);
      const int e2 = __shfl(idx, jj + 2, 64);
      const int e3 = __shfl(idx, jj + 3, 64);
      const float f0 = Xe[(size_t)e0 * 64 + lane];
      const float f1 = Xe[(size_t)e1 * 64 + lane];
      const float f2 = Xe[(size_t)e2 * 64 + lane];
      const float f3 = Xe[(size_t)e3 * 64 + lane];
      acc += (f0 + f1) + (f2 + f3);
    }
    for (; jj < n; ++jj) {
      const int e = __shfl(idx, jj, 64);
      acc += Xe[(size_t)e * 64 + lane];
    }
  }
  out[(size_t)v * 64 + lane] = acc * degV[v];
}

// ===========================================================================
extern "C" void kernel_launch(void* const* d_in, const int* in_sizes, int n_in,
                              void* d_out, int out_size, void* d_ws, size_t ws_size,
                              hipStream_t stream) {
  const float* X      = (const float*)d_in[0];
  const int*   vertex = (const int*)d_in[1];
  const int*   edges  = (const int*)d_in[2];
  const float* W      = (const float*)d_in[3];
  const float* degE   = (const float*)d_in[4];
  const float* degV   = (const float*)d_in[5];
  const float* W_edge = (const float*)d_in[6];
  float* out = (float*)d_out;

  const int nnz = in_sizes[1];
  const int E   = in_sizes[4];
  const int N   = in_sizes[5];
  const int M   = E + N;
  const int NB  = (M + 2047) / 2048;

  char* p = (char*)d_ws;
  auto alloc = [&](size_t bytes) -> void* {
    void* r = (void*)p;
    p += (bytes + 255) & ~(size_t)255;
    return r;
  };
  int*   counts = (int*)alloc((size_t)M * 4);
  int*   offs   = (int*)alloc((size_t)(M + 1) * 4);
  int*   pos    = (int*)alloc((size_t)M * 4);
  int*   bsums  = (int*)alloc(4096);
  int*   perm   = (int*)alloc((size_t)2 * nnz * 4);
  bf16*  Xl     = (bf16*)alloc((size_t)N * 64 * 2);
  float* Xe     = (float*)alloc((size_t)E * 64 * 4);

  const int nchunks = (nnz + CHUNK - 1) / CHUNK;
  const int pgrid   = nchunks * NPART;

  hipMemsetAsync(counts, 0, (size_t)M * 4, stream);
  hist_kernel<<<pgrid, 256, 0, stream>>>(vertex, edges, counts, nnz, E, N);
  scan_blocks_kernel<<<NB, 256, 0, stream>>>(counts, offs, bsums, M);
  scan_sums_kernel<<<1, 64, 0, stream>>>(bsums, offs, NB, M);
  scan_add_kernel<<<NB, 256, 0, stream>>>(offs, pos, bsums, M);
  fill_kernel<<<pgrid, 256, 0, stream>>>(vertex, edges, pos, perm, nnz, E, N);

  gemm_kernel<<<(N + 31) / 32, 256, 0, stream>>>(X, W, Xl, N);
  gather_e_kernel<<<(E + 3) / 4, 256, 0, stream>>>(Xl, perm, offs, degE, W_edge, Xe, E);
  gather_v_kernel<<<(N + 3) / 4, 256, 0, stream>>>(Xe, perm, offs, degV, out, N, E);
}